// Round 2
// baseline (3065.125 us; speedup 1.0000x reference)
//
#include <hip/hip_runtime.h>

// ---------------------------------------------------------------------------
// 2-layer GCN, bucketed edge aggregation (no exact CSR, no global f32 atomics).
//   bucket b = dst >> 7  (128-node windows, NB = ceil(N/128) = 782)
//   ebuf[] holds edges grouped by bucket, packed as  src | (dst&127)<<20
//   per-bucket agg: 128x64 f32 LDS accumulator, ds_add_f32, fused epilogue.
//   out[i] = dinv[i] * ( sum_{s in in(i)} G[s] + G[i] ),  G = rowscale(X@W, dinv)
// ---------------------------------------------------------------------------

#define EBLK 8192  // edges per bucketing block

__global__ __launch_bounds__(256) void bcount_k(const int* __restrict__ dst,
                                                int* __restrict__ bcnt, int E, int NB) {
    __shared__ int h[1024];
    int t = threadIdx.x;
#pragma unroll
    for (int j = 0; j < 4; j++) h[t + 256 * j] = 0;
    __syncthreads();
    int base = blockIdx.x * EBLK;
#pragma unroll 4
    for (int r = 0; r < 32; r++) {
        int i = base + r * 256 + t;
        if (i < E) atomicAdd(&h[((unsigned)dst[i]) >> 7], 1);
    }
    __syncthreads();
    for (int j = t; j < NB; j += 256)
        if (h[j]) atomicAdd(&bcnt[j], h[j]);
}

__global__ __launch_bounds__(1024) void bscan_k(const int* __restrict__ bcnt,
                                                int* __restrict__ boff,
                                                int* __restrict__ bcur, int NB) {
    __shared__ int s[1024];
    int t = threadIdx.x;
    int v = (t < NB) ? bcnt[t] : 0;
    s[t] = v;
    __syncthreads();
    for (int d = 1; d < 1024; d <<= 1) {
        int x = (t >= d) ? s[t - d] : 0;
        __syncthreads();
        s[t] += x;
        __syncthreads();
    }
    if (t < NB) {
        boff[t + 1] = s[t];
        if (t == 0) boff[0] = 0;
        bcur[t] = s[t] - v;  // exclusive
    }
}

__global__ __launch_bounds__(256) void bfill_k(const int* __restrict__ src,
                                               const int* __restrict__ dst,
                                               int* __restrict__ bcur,
                                               int* __restrict__ ebuf, int E, int NB) {
    __shared__ int h[1024];
    __shared__ int bbase[1024];
    __shared__ int rank[1024];
    int t = threadIdx.x;
#pragma unroll
    for (int j = 0; j < 4; j++) { h[t + 256 * j] = 0; rank[t + 256 * j] = 0; }
    __syncthreads();
    int base = blockIdx.x * EBLK;
#pragma unroll 4
    for (int r = 0; r < 32; r++) {
        int i = base + r * 256 + t;
        if (i < E) atomicAdd(&h[((unsigned)dst[i]) >> 7], 1);
    }
    __syncthreads();
    for (int j = t; j < NB; j += 256)
        if (h[j]) bbase[j] = atomicAdd(&bcur[j], h[j]);
    __syncthreads();
#pragma unroll 4
    for (int r = 0; r < 32; r++) {
        int i = base + r * 256 + t;
        if (i < E) {
            int d = dst[i];
            int b = ((unsigned)d) >> 7;
            int rk = atomicAdd(&rank[b], 1);
            ebuf[bbase[b] + rk] = src[i] | ((d & 127) << 20);
        }
    }
}

// Per-bucket in-degree (each node in exactly one bucket -> no global atomics).
__global__ __launch_bounds__(256) void deg_k(const int* __restrict__ ebuf,
                                             const int* __restrict__ boff,
                                             float* __restrict__ dinv, int n) {
    __shared__ int c[128];
    int t = threadIdx.x;
    if (t < 128) c[t] = 0;
    __syncthreads();
    int b = blockIdx.x;
    int s0 = boff[b], s1 = boff[b + 1];
    for (int i = s0 + t; i < s1; i += 256)
        atomicAdd(&c[((unsigned)ebuf[i]) >> 20], 1);
    __syncthreads();
    if (t < 128) {
        int gn = (b << 7) + t;
        if (gn < n) dinv[gn] = rsqrtf((float)(c[t] + 1));
    }
}

// G[r][:] = dinv[r] * (X[r][:] @ W).  Thread-per-row, W staged in LDS.
__global__ __launch_bounds__(256) void gemm64_scale_k(
    const float* __restrict__ X, const float* __restrict__ W,
    const float* __restrict__ dinv, float* __restrict__ G, int n) {
    __shared__ float wl[64 * 64];
    int t = threadIdx.x;
#pragma unroll
    for (int u = 0; u < 16; u++) wl[t + 256 * u] = W[t + 256 * u];
    __syncthreads();
    int r = blockIdx.x * 256 + t;
    if (r >= n) return;

    const float4* xp = (const float4*)(X + (size_t)r * 64);
    float4 acc[16];
#pragma unroll
    for (int j = 0; j < 16; j++) acc[j] = make_float4(0.f, 0.f, 0.f, 0.f);

    for (int i = 0; i < 16; i++) {
        float4 xv = xp[i];
#pragma unroll
        for (int c = 0; c < 4; c++) {
            float xk = (c == 0) ? xv.x : (c == 1) ? xv.y : (c == 2) ? xv.z : xv.w;
            const float4* wr = (const float4*)(wl + (i * 4 + c) * 64);
#pragma unroll
            for (int j = 0; j < 16; j++) {
                float4 wv = wr[j];
                acc[j].x = fmaf(xk, wv.x, acc[j].x);
                acc[j].y = fmaf(xk, wv.y, acc[j].y);
                acc[j].z = fmaf(xk, wv.z, acc[j].z);
                acc[j].w = fmaf(xk, wv.w, acc[j].w);
            }
        }
    }
    float sc = dinv[r];
    float4* gp = (float4*)(G + (size_t)r * 64);
#pragma unroll
    for (int j = 0; j < 16; j++) {
        float4 v = acc[j];
        v.x *= sc; v.y *= sc; v.z *= sc; v.w *= sc;
        gp[j] = v;
    }
}

// Bucket aggregation: 128x64 f32 LDS tile, edge-parallel ds_add_f32.
// FINAL=0: Out[node][lane] = relu(dinv*acc + bias[lane])
// FINAL=1: Out[node] = relu(...) . Wl + bl   (wave reduce)
template <int FINAL>
__global__ __launch_bounds__(256) void agg_k(
    const float* __restrict__ G, const int* __restrict__ ebuf,
    const int* __restrict__ boff, const float* __restrict__ dinv,
    const float* __restrict__ bias, const float* __restrict__ Wl,
    const float* __restrict__ bl, float* __restrict__ Out, int n) {
    __shared__ float acc[128 * 64];  // 32 KiB
    int t = threadIdx.x;
    int lane = t & 63, wid = t >> 6;
    int b = blockIdx.x;
    int nbase = b << 7;

    // init with self-loop term G[node][:]
#pragma unroll
    for (int j = 0; j < 32; j++) {
        int idx = j * 256 + t;
        int row = nbase + (idx >> 6);
        acc[idx] = (row < n) ? G[(size_t)nbase * 64 + idx] : 0.f;
    }
    __syncthreads();

    int s0 = boff[b], s1 = boff[b + 1];
    for (int cb = s0 + wid * 64; cb < s1; cb += 256) {
        int m = s1 - cb;
        if (m > 64) m = 64;
        int e = (lane < m) ? ebuf[cb + lane] : 0;
        for (int u = 0; u < m; u++) {
            int se = __shfl(e, u);
            int srow = se & 0xFFFFF;
            int l = ((unsigned)se) >> 20;
            atomicAdd(&acc[(l << 6) + lane], G[(size_t)srow * 64 + lane]);
        }
    }
    __syncthreads();

    for (int nl = wid; nl < 128; nl += 4) {
        int gn = nbase + nl;
        if (gn >= n) break;
        float v = fmaf(dinv[gn], acc[(nl << 6) + lane], bias[lane]);
        v = fmaxf(v, 0.f);
        if (FINAL) {
            float p = v * Wl[lane];
#pragma unroll
            for (int d = 32; d > 0; d >>= 1) p += __shfl_xor(p, d);
            if (lane == 0) Out[gn] = p + bl[0];
        } else {
            Out[(size_t)gn * 64 + lane] = v;
        }
    }
}

extern "C" void kernel_launch(void* const* d_in, const int* in_sizes, int n_in,
                              void* d_out, int out_size, void* d_ws, size_t ws_size,
                              hipStream_t stream) {
    const float* x  = (const float*)d_in[0];
    const int*   ei = (const int*)d_in[1];
    const float* W1 = (const float*)d_in[2];
    const float* b1 = (const float*)d_in[3];
    const float* W2 = (const float*)d_in[4];
    const float* b2 = (const float*)d_in[5];
    const float* Wl = (const float*)d_in[6];
    const float* bl = (const float*)d_in[7];

    const int N = in_sizes[0] / 64;
    const int E = in_sizes[1] / 2;
    const int* src = ei;
    const int* dst = ei + E;
    const int NB = (N + 127) >> 7;            // 782 for N=100k (<=1024 assumed)
    const int FB = (E + EBLK - 1) / EBLK;     // 391

    char* w = (char*)d_ws;
    size_t o = 0;
    auto take = [&](size_t bytes) {
        void* p = w + o;
        o = (o + bytes + 255) & ~(size_t)255;
        return p;
    };
    int*   bcnt = (int*)take((size_t)NB * 4);
    int*   bcur = (int*)take((size_t)NB * 4);
    int*   boff = (int*)take((size_t)(NB + 1) * 4);
    float* dinv = (float*)take((size_t)N * 4);
    int*   ebuf = (int*)take((size_t)E * 4);
    float* bufA = (float*)take((size_t)N * 64 * 4);
    float* bufB = (float*)take((size_t)N * 64 * 4);

    hipMemsetAsync(bcnt, 0, (size_t)NB * 4, stream);
    bcount_k<<<FB, 256, 0, stream>>>(dst, bcnt, E, NB);
    bscan_k<<<1, 1024, 0, stream>>>(bcnt, boff, bcur, NB);
    bfill_k<<<FB, 256, 0, stream>>>(src, dst, bcur, ebuf, E, NB);
    deg_k<<<NB, 256, 0, stream>>>(ebuf, boff, dinv, N);

    // Layer 1
    gemm64_scale_k<<<(N + 255) / 256, 256, 0, stream>>>(x, W1, dinv, bufA, N);
    agg_k<0><<<NB, 256, 0, stream>>>(bufA, ebuf, boff, dinv, b1, nullptr, nullptr,
                                     bufB, N);
    // Layer 2 + fused linear head
    gemm64_scale_k<<<(N + 255) / 256, 256, 0, stream>>>(bufB, W2, dinv, bufA, N);
    agg_k<1><<<NB, 256, 0, stream>>>(bufA, ebuf, boff, dinv, b2, Wl, bl,
                                     (float*)d_out, N);
}

// Round 4
// 439.620 us; speedup vs baseline: 6.9722x; 6.9722x over previous
//
#include <hip/hip_runtime.h>

// ---------------------------------------------------------------------------
// 2-layer GCN on MI355X.
// CSR built via bucket-chunked reorder (no random 4B global scatter, no
// global f32 atomics):
//   bucket b = dst >> 7 (128-node windows), ebuf packed as src | (dst&127)<<20
//   csr_k: per bucket, LDS count + scan -> exact per-node CSR + dinv.
// Aggregation: wave-per-node gather, quad-per-edge float4 (4 edges in flight
// per load group, 16B/lane), butterfly merge. G = rowscale(X@W, dinv).
//   out[i] = relu(dinv[i]*(G[i] + sum_{s in in(i)} G[s]) + b)
// Final linear head fused into layer-2 aggregation.
// ---------------------------------------------------------------------------

#define EBLK 8192  // edges per bucketing block

__global__ __launch_bounds__(256) void bcount_k(const int* __restrict__ dst,
                                                int* __restrict__ bcnt, int E, int NB) {
    __shared__ int h[1024];
    int t = threadIdx.x;
#pragma unroll
    for (int j = 0; j < 4; j++) h[t + 256 * j] = 0;
    __syncthreads();
    int base = blockIdx.x * EBLK;
#pragma unroll 4
    for (int r = 0; r < 32; r++) {
        int i = base + r * 256 + t;
        if (i < E) atomicAdd(&h[((unsigned)dst[i]) >> 7], 1);
    }
    __syncthreads();
    for (int j = t; j < NB; j += 256)
        if (h[j]) atomicAdd(&bcnt[j], h[j]);
}

__global__ __launch_bounds__(1024) void bscan_k(const int* __restrict__ bcnt,
                                                int* __restrict__ boff,
                                                int* __restrict__ bcur, int NB) {
    __shared__ int s[1024];
    int t = threadIdx.x;
    int v = (t < NB) ? bcnt[t] : 0;
    s[t] = v;
    __syncthreads();
    for (int d = 1; d < 1024; d <<= 1) {
        int x = (t >= d) ? s[t - d] : 0;
        __syncthreads();
        s[t] += x;
        __syncthreads();
    }
    if (t < NB) {
        boff[t + 1] = s[t];
        if (t == 0) boff[0] = 0;
        bcur[t] = s[t] - v;  // exclusive
    }
}

__global__ __launch_bounds__(256) void bfill_k(const int* __restrict__ src,
                                               const int* __restrict__ dst,
                                               int* __restrict__ bcur,
                                               int* __restrict__ ebuf, int E, int NB) {
    __shared__ int h[1024];
    __shared__ int bbase[1024];
    __shared__ int rank[1024];
    int t = threadIdx.x;
#pragma unroll
    for (int j = 0; j < 4; j++) { h[t + 256 * j] = 0; rank[t + 256 * j] = 0; }
    __syncthreads();
    int base = blockIdx.x * EBLK;
#pragma unroll 4
    for (int r = 0; r < 32; r++) {
        int i = base + r * 256 + t;
        if (i < E) atomicAdd(&h[((unsigned)dst[i]) >> 7], 1);
    }
    __syncthreads();
    for (int j = t; j < NB; j += 256)
        if (h[j]) bbase[j] = atomicAdd(&bcur[j], h[j]);
    __syncthreads();
#pragma unroll 4
    for (int r = 0; r < 32; r++) {
        int i = base + r * 256 + t;
        if (i < E) {
            int d = dst[i];
            int b = ((unsigned)d) >> 7;
            int rk = atomicAdd(&rank[b], 1);
            ebuf[bbase[b] + rk] = src[i] | ((d & 127) << 20);
        }
    }
}

// One block per bucket: exact per-node CSR within the bucket's contiguous
// region + node offsets + dinv. ebuf read twice (L2-resident), csr writes
// land inside a ~16KB contiguous window.
__global__ __launch_bounds__(256) void csr_k(const int* __restrict__ ebuf,
                                             const int* __restrict__ boff,
                                             int* __restrict__ off,
                                             int* __restrict__ csr,
                                             float* __restrict__ dinv, int n, int E) {
    __shared__ int cnt[128];
    __shared__ int pre[128];
    __shared__ int cur[128];
    int t = threadIdx.x;
    if (t < 128) cnt[t] = 0;
    __syncthreads();
    int b = blockIdx.x;
    int s0 = boff[b], s1 = boff[b + 1];
    for (int i = s0 + t; i < s1; i += 256)
        atomicAdd(&cnt[((unsigned)ebuf[i]) >> 20], 1);
    __syncthreads();
    if (t < 128) pre[t] = cnt[t];
    __syncthreads();
    for (int d = 1; d < 128; d <<= 1) {
        int v = (t >= d && t < 128) ? pre[t - d] : 0;
        __syncthreads();
        if (t < 128) pre[t] += v;
        __syncthreads();
    }
    if (t < 128) {
        int excl = pre[t] - cnt[t];
        cur[t] = excl;
        int gn = (b << 7) + t;
        if (gn < n) {
            off[gn] = s0 + excl;
            dinv[gn] = rsqrtf((float)(cnt[t] + 1));
        }
    }
    if (t == 0 && b == gridDim.x - 1) off[n] = E;
    __syncthreads();
    for (int i = s0 + t; i < s1; i += 256) {
        int v = ebuf[i];
        int l = ((unsigned)v) >> 20;
        int rk = atomicAdd(&cur[l], 1);
        csr[s0 + rk] = v & 0xFFFFF;
    }
}

// G[r][:] = dinv[r] * (X[r][:] @ W).  Thread-per-row, W staged in LDS.
__global__ __launch_bounds__(256) void gemm64_scale_k(
    const float* __restrict__ X, const float* __restrict__ W,
    const float* __restrict__ dinv, float* __restrict__ G, int n) {
    __shared__ float wl[64 * 64];
    int t = threadIdx.x;
#pragma unroll
    for (int u = 0; u < 16; u++) wl[t + 256 * u] = W[t + 256 * u];
    __syncthreads();
    int r = blockIdx.x * 256 + t;
    if (r >= n) return;

    const float4* xp = (const float4*)(X + (size_t)r * 64);
    float4 acc[16];
#pragma unroll
    for (int j = 0; j < 16; j++) acc[j] = make_float4(0.f, 0.f, 0.f, 0.f);

    for (int i = 0; i < 16; i++) {
        float4 xv = xp[i];
#pragma unroll
        for (int c = 0; c < 4; c++) {
            float xk = (c == 0) ? xv.x : (c == 1) ? xv.y : (c == 2) ? xv.z : xv.w;
            const float4* wr = (const float4*)(wl + (i * 4 + c) * 64);
#pragma unroll
            for (int j = 0; j < 16; j++) {
                float4 wv = wr[j];
                acc[j].x = fmaf(xk, wv.x, acc[j].x);
                acc[j].y = fmaf(xk, wv.y, acc[j].y);
                acc[j].z = fmaf(xk, wv.z, acc[j].z);
                acc[j].w = fmaf(xk, wv.w, acc[j].w);
            }
        }
    }
    float sc = dinv[r];
    float4* gp = (float4*)(G + (size_t)r * 64);
#pragma unroll
    for (int j = 0; j < 16; j++) {
        float4 v = acc[j];
        v.x *= sc; v.y *= sc; v.z *= sc; v.w *= sc;
        gp[j] = v;
    }
}

__device__ inline float4 ld4(const float* p) { return *(const float4*)p; }
__device__ inline void add4(float4& a, float4 g) {
    a.x += g.x; a.y += g.y; a.z += g.z; a.w += g.w;
}
__device__ inline void bfly4(float4& a, int m) {
    a.x += __shfl_xor(a.x, m);
    a.y += __shfl_xor(a.y, m);
    a.z += __shfl_xor(a.z, m);
    a.w += __shfl_xor(a.w, m);
}

// Wave-per-node aggregation, quad-per-edge float4 gather.
// lane = 16*q + fcol; quad q handles edge u+q; 16 lanes x float4 = 256B row.
// FINAL=0: Out[node][:] = relu(dinv*acc + bias)
// FINAL=1: Out[node] = relu(...) . Wl + bl
template <int FINAL>
__global__ __launch_bounds__(256) void agg_k(
    const float* __restrict__ G, const int* __restrict__ csr,
    const int* __restrict__ off, const float* __restrict__ dinv,
    const float* __restrict__ bias, const float* __restrict__ Wl,
    const float* __restrict__ bl, float* __restrict__ Out, int n) {
    int lane = threadIdx.x & 63;
    int wid = threadIdx.x >> 6;
    int node = blockIdx.x * 4 + wid;
    if (node >= n) return;

    int q = lane >> 4;
    int fl = (lane & 15) << 2;  // feature base for this lane's float4

    float4 a = make_float4(0.f, 0.f, 0.f, 0.f);
    if (q == 0) a = ld4(G + (size_t)node * 64 + fl);  // self-loop term

    int s0 = off[node], s1 = off[node + 1];
    for (int base = s0; base < s1; base += 64) {
        int m = s1 - base;
        if (m > 64) m = 64;
        int e = (lane < m) ? csr[base + lane] : 0;
        int u = 0;
        for (; u + 16 <= m; u += 16) {
            int e0 = __shfl(e, u + q);
            int e1 = __shfl(e, u + 4 + q);
            int e2 = __shfl(e, u + 8 + q);
            int e3 = __shfl(e, u + 12 + q);
            float4 g0 = ld4(G + (size_t)e0 * 64 + fl);
            float4 g1 = ld4(G + (size_t)e1 * 64 + fl);
            float4 g2 = ld4(G + (size_t)e2 * 64 + fl);
            float4 g3 = ld4(G + (size_t)e3 * 64 + fl);
            add4(a, g0); add4(a, g1); add4(a, g2); add4(a, g3);
        }
        for (; u + 4 <= m; u += 4) {
            int e0 = __shfl(e, u + q);
            add4(a, ld4(G + (size_t)e0 * 64 + fl));
        }
        if (u < m) {  // tail of 1..3 edges (u, m wave-uniform)
            int e0 = __shfl(e, (u + q < m) ? (u + q) : 0);
            if (u + q < m) add4(a, ld4(G + (size_t)e0 * 64 + fl));
        }
    }
    // merge quads: butterfly across lane bits 4,5
    bfly4(a, 16);
    bfly4(a, 32);

    float di = dinv[node];
    float4 bv = ld4(bias + fl);
    float4 v;
    v.x = fmaxf(fmaf(di, a.x, bv.x), 0.f);
    v.y = fmaxf(fmaf(di, a.y, bv.y), 0.f);
    v.z = fmaxf(fmaf(di, a.z, bv.z), 0.f);
    v.w = fmaxf(fmaf(di, a.w, bv.w), 0.f);

    if (FINAL) {
        float4 wv = ld4(Wl + fl);
        float p = v.x * wv.x + v.y * wv.y + v.z * wv.z + v.w * wv.w;
#pragma unroll
        for (int d = 8; d > 0; d >>= 1) p += __shfl_xor(p, d);
        if (lane == 0) Out[node] = p + bl[0];
    } else {
        if (q == 0) *(float4*)(Out + (size_t)node * 64 + fl) = v;
    }
}

extern "C" void kernel_launch(void* const* d_in, const int* in_sizes, int n_in,
                              void* d_out, int out_size, void* d_ws, size_t ws_size,
                              hipStream_t stream) {
    const float* x  = (const float*)d_in[0];
    const int*   ei = (const int*)d_in[1];
    const float* W1 = (const float*)d_in[2];
    const float* b1 = (const float*)d_in[3];
    const float* W2 = (const float*)d_in[4];
    const float* b2 = (const float*)d_in[5];
    const float* Wl = (const float*)d_in[6];
    const float* bl = (const float*)d_in[7];

    const int N = in_sizes[0] / 64;
    const int E = in_sizes[1] / 2;
    const int* src = ei;
    const int* dst = ei + E;
    const int NB = (N + 127) >> 7;         // 782 buckets (<=1024 assumed)
    const int FB = (E + EBLK - 1) / EBLK;  // 391

    char* w = (char*)d_ws;
    size_t o = 0;
    auto take = [&](size_t bytes) {
        void* p = w + o;
        o = (o + bytes + 255) & ~(size_t)255;
        return p;
    };
    int*   bcnt = (int*)take((size_t)NB * 4);
    int*   bcur = (int*)take((size_t)NB * 4);
    int*   boff = (int*)take((size_t)(NB + 1) * 4);
    float* dinv = (float*)take((size_t)N * 4);
    int*   off  = (int*)take((size_t)(N + 1) * 4);
    int*   ebuf = (int*)take((size_t)E * 4);
    int*   csr  = (int*)take((size_t)E * 4);
    float* bufA = (float*)take((size_t)N * 64 * 4);
    float* bufB = (float*)take((size_t)N * 64 * 4);

    hipMemsetAsync(bcnt, 0, (size_t)NB * 4, stream);
    bcount_k<<<FB, 256, 0, stream>>>(dst, bcnt, E, NB);
    bscan_k<<<1, 1024, 0, stream>>>(bcnt, boff, bcur, NB);
    bfill_k<<<FB, 256, 0, stream>>>(src, dst, bcur, ebuf, E, NB);
    csr_k<<<NB, 256, 0, stream>>>(ebuf, boff, off, csr, dinv, N, E);

    // Layer 1
    gemm64_scale_k<<<(N + 255) / 256, 256, 0, stream>>>(x, W1, dinv, bufA, N);
    agg_k<0><<<(N + 3) / 4, 256, 0, stream>>>(bufA, csr, off, dinv, b1, nullptr,
                                              nullptr, bufB, N);
    // Layer 2 + fused linear head
    gemm64_scale_k<<<(N + 255) / 256, 256, 0, stream>>>(bufB, W2, dinv, bufA, N);
    agg_k<1><<<(N + 3) / 4, 256, 0, stream>>>(bufA, csr, off, dinv, b2, Wl, bl,
                                              (float*)d_out, N);
}